// Round 1
// baseline (71536.676 us; speedup 1.0000x reference)
//
#include <hip/hip_runtime.h>
#include <math.h>

#define HID   1024
#define SEQL  512
#define NB    64
#define DIN0  512

__device__ __forceinline__ float sigm_(float x) {
    return 1.0f / (1.0f + __expf(-x));
}
__device__ __forceinline__ float tanh_(float x) {
    // stable tanh via exp of negative argument
    float ax = fabsf(x);
    float e = __expf(-2.0f * ax);
    float t = (1.0f - e) / (1.0f + e);
    return copysignf(t, x);
}

// One GRU step for one layer.
// Each thread computes one h element (b, j): 3 input-side dots over Din and
// 3 hidden-side dots over HID, then the gate pointwise math.
// Block: 256 threads = 64 batches x 4 columns. Grid: 256 blocks -> j in [0,1024).
__global__ __launch_bounds__(256) void gru_step(
    const float* __restrict__ xin, long xbs,   // input rows, batch stride
    const float* __restrict__ hprev,           // [64][1024] this layer's prev h
    const float* __restrict__ Wih,             // [3H][Din]
    const float* __restrict__ Whh,             // [3H][H]
    const float* __restrict__ bih,
    const float* __restrict__ bhh,
    int Din,
    float* __restrict__ hout,                  // [64][1024]
    float* __restrict__ out1, long obs)        // optional extra output (layer 1)
{
    const int tid = threadIdx.x;
    const int b   = tid & 63;
    const int jj  = tid >> 6;
    const int j   = (int)blockIdx.x * 4 + jj;
    // j is wave-uniform (tid>>6 constant within a 64-lane wave); make it
    // provably uniform so W/b accesses become scalar loads.
    const int js  = __builtin_amdgcn_readfirstlane(j);

    const float4* __restrict__ xv4 = (const float4*)(xin + (long)b * xbs);
    const float4* __restrict__ hv4 = (const float4*)(hprev + (long)b * HID);

    // ---- input-side gates: gi = x . Wih^T + bih ----
    const float4* __restrict__ wir = (const float4*)(Wih + (long)js * Din);
    const float4* __restrict__ wiz = (const float4*)(Wih + (long)(HID + js) * Din);
    const float4* __restrict__ win = (const float4*)(Wih + (long)(2 * HID + js) * Din);
    float ar = 0.f, az = 0.f, an = 0.f;
    const int n4i = Din >> 2;
#pragma unroll 4
    for (int k = 0; k < n4i; ++k) {
        float4 xv = xv4[k];
        float4 r4 = wir[k];
        float4 z4 = wiz[k];
        float4 m4 = win[k];
        ar += xv.x * r4.x + xv.y * r4.y + xv.z * r4.z + xv.w * r4.w;
        az += xv.x * z4.x + xv.y * z4.y + xv.z * z4.z + xv.w * z4.w;
        an += xv.x * m4.x + xv.y * m4.y + xv.z * m4.z + xv.w * m4.w;
    }
    ar += bih[js];
    az += bih[HID + js];
    an += bih[2 * HID + js];

    // ---- hidden-side gates: gh = h . Whh^T + bhh ----
    const float4* __restrict__ whr = (const float4*)(Whh + (long)js * HID);
    const float4* __restrict__ whz = (const float4*)(Whh + (long)(HID + js) * HID);
    const float4* __restrict__ whn = (const float4*)(Whh + (long)(2 * HID + js) * HID);
    float hr = 0.f, hz = 0.f, hn = 0.f;
    const int n4h = HID >> 2;
#pragma unroll 4
    for (int k = 0; k < n4h; ++k) {
        float4 hv = hv4[k];
        float4 r4 = whr[k];
        float4 z4 = whz[k];
        float4 m4 = whn[k];
        hr += hv.x * r4.x + hv.y * r4.y + hv.z * r4.z + hv.w * r4.w;
        hz += hv.x * z4.x + hv.y * z4.y + hv.z * z4.z + hv.w * z4.w;
        hn += hv.x * m4.x + hv.y * m4.y + hv.z * m4.z + hv.w * m4.w;
    }
    hr += bhh[js];
    hz += bhh[HID + js];
    hn += bhh[2 * HID + js];

    // ---- gate math (matches the reference exactly) ----
    const float r = sigm_(ar + hr);
    const float z = sigm_(az + hz);
    const float n = tanh_(an + r * hn);
    const float hv = hprev[(long)b * HID + j];
    const float hnew = (1.0f - z) * hv + z * n;

    hout[(long)b * HID + j] = hnew;
    if (out1) out1[(long)b * obs + j] = hnew;
}

extern "C" void kernel_launch(void* const* d_in, const int* in_sizes, int n_in,
                              void* d_out, int out_size, void* d_ws, size_t ws_size,
                              hipStream_t stream) {
    const float* x    = (const float*)d_in[0];
    const float* h0   = (const float*)d_in[1];
    const float* Wih0 = (const float*)d_in[2];
    const float* Whh0 = (const float*)d_in[3];
    const float* bih0 = (const float*)d_in[4];
    const float* bhh0 = (const float*)d_in[5];
    const float* Wih1 = (const float*)d_in[6];
    const float* Whh1 = (const float*)d_in[7];
    const float* bih1 = (const float*)d_in[8];
    const float* bhh1 = (const float*)d_in[9];

    float* out   = (float*)d_out;                      // [64][512][1024]
    float* hnout = out + (long)NB * SEQL * HID;        // [2][64][1024]

    // ws: two ping-pong h-state buffers, each [2 layers][64][1024] fp32 = 512KB
    float* buf0 = (float*)d_ws;
    float* buf1 = buf0 + 2L * NB * HID;

    // h state starts at h0 (layout [2][64][1024] matches buffer layout)
    hipMemcpyAsync(buf0, h0, 2L * NB * HID * sizeof(float),
                   hipMemcpyDeviceToDevice, stream);

    for (int t = 0; t < SEQL; ++t) {
        float* hp = (t & 1) ? buf1 : buf0;   // read
        float* hc = (t & 1) ? buf0 : buf1;   // write
        // layer 0: input = x[:, t, :], batch stride SEQ*DIN0
        gru_step<<<256, 256, 0, stream>>>(
            x + (long)t * DIN0, (long)SEQL * DIN0,
            hp, Wih0, Whh0, bih0, bhh0, DIN0,
            hc, nullptr, 0);
        // layer 1: input = layer 0's new h (just written), its own h at offset NB*HID
        gru_step<<<256, 256, 0, stream>>>(
            hc, (long)HID,
            hp + (long)NB * HID, Wih1, Whh1, bih1, bhh1, HID,
            hc + (long)NB * HID,
            out + (long)t * HID, (long)SEQL * HID);
    }
    // after t=511 (odd), final h sits in buf0 = [hT0; hT1]
    hipMemcpyAsync(hnout, buf0, 2L * NB * HID * sizeof(float),
                   hipMemcpyDeviceToDevice, stream);
}

// Round 2
// 17143.147 us; speedup vs baseline: 4.1729x; 4.1729x over previous
//
#include <hip/hip_runtime.h>
#include <hip/hip_bf16.h>
#include <math.h>

#define HID 1024
#define SEQ 512
#define NB  64
#define DIN 512

using short8 = __attribute__((ext_vector_type(8))) short;
using f32x4  = __attribute__((ext_vector_type(4))) float;

__device__ __forceinline__ unsigned short f2bf(float f) {
    unsigned int u = __float_as_uint(f);
    u += 0x7fffu + ((u >> 16) & 1u);          // round-to-nearest-even
    return (unsigned short)(u >> 16);
}
__device__ __forceinline__ float sigm_(float x) { return 1.0f / (1.0f + __expf(-x)); }
__device__ __forceinline__ float tanh_(float x) {
    float ax = fabsf(x);
    float e = __expf(-2.0f * ax);
    float t = (1.0f - e) / (1.0f + e);
    return copysignf(t, x);
}

// XOR-swizzled LDS byte address for a [64][512] bf16 tile (row stride 1024 B).
// G4 pattern: spreads the 16-lane same-column ds_read_b128 across banks.
#define SWZ(row, byteinrow) (((((row) << 10) + (byteinrow))) ^ (((row) & 7) << 4))

// Fused step: blocks [0,64) run layer 0 at time t; blocks [64,128) run layer 1
// at time t-1 (pipeline skew; the two are independent within one launch).
// Block: 256 thr = 4 waves; wave w owns m-tile w (16 batches), computes
// [16m x 16j] for all 3 gates via mfma_f32_16x16x32_bf16, K streamed in
// 512-wide LDS chunks. Pointwise GRU update is per-lane (no cross-thread).
__global__ __launch_bounds__(256) void gru_step(
    int t, const float* __restrict__ x,
    const unsigned short* __restrict__ W0i, const unsigned short* __restrict__ W0h,
    const unsigned short* __restrict__ W1i, const unsigned short* __restrict__ W1h,
    const float* __restrict__ bi0, const float* __restrict__ bh0,
    const float* __restrict__ bi1, const float* __restrict__ bh1,
    float* __restrict__ hf,          // [2 layer][2 parity][64][1024] fp32 state
    unsigned short* __restrict__ hb, // same layout, bf16 state (MFMA A-operand)
    float* __restrict__ out)         // [64][512][1024]
{
    const int bid   = blockIdx.x;
    const int layer = bid >> 6;
    const int jb    = bid & 63;
    const int s     = layer ? (t - 1) : t;
    if (layer == 0 && t >= SEQ) return;
    if (layer == 1 && t == 0)  return;
    const int rp = s & 1, wp = rp ^ 1;

    const int tid = threadIdx.x;
    const int l   = tid & 63;
    const int w   = tid >> 6;
    const int j0  = jb << 4;

    __shared__ __align__(16) unsigned char ldsA[NB * 1024];  // [64][512] bf16, swizzled

    f32x4 acc_r = {0,0,0,0}, acc_z = {0,0,0,0}, acc_n = {0,0,0,0}, acc_nx = {0,0,0,0};

    const int nchunks = layer ? 4 : 3;   // L0: x(512)+h(2x512); L1: out0(2x512)+h(2x512)
    const int srow = tid >> 2;           // staging: 4 threads per row
    const int e0   = (tid & 3) << 7;     // 128 elems each

    for (int c = 0; c < nchunks; ++c) {
        __syncthreads();
        // ---- stage A chunk [64][512] bf16 into swizzled LDS ----
        if (layer == 0 && c == 0) {
            const float* src = x + ((long)srow * SEQ + s) * DIN;
#pragma unroll 4
            for (int p = 0; p < 16; ++p) {
                const int e = e0 + (p << 3);
                float4 f0 = *(const float4*)(src + e);
                float4 f1 = *(const float4*)(src + e + 4);
                short8 pk;
                pk[0] = (short)f2bf(f0.x); pk[1] = (short)f2bf(f0.y);
                pk[2] = (short)f2bf(f0.z); pk[3] = (short)f2bf(f0.w);
                pk[4] = (short)f2bf(f1.x); pk[5] = (short)f2bf(f1.y);
                pk[6] = (short)f2bf(f1.z); pk[7] = (short)f2bf(f1.w);
                *(short8*)(ldsA + SWZ(srow, e << 1)) = pk;
            }
        } else {
            const unsigned short* src;
            if (layer == 0)      src = hb + ((long)(0*2 + rp) * NB + srow) * HID + (c - 1) * 512;
            else if (c < 2)      src = hb + ((long)(0*2 + wp) * NB + srow) * HID + c * 512;       // out0[s]
            else                 src = hb + ((long)(1*2 + rp) * NB + srow) * HID + (c - 2) * 512; // h1[s-1]
#pragma unroll 4
            for (int p = 0; p < 16; ++p) {
                const int e = e0 + (p << 3);
                *(short8*)(ldsA + SWZ(srow, e << 1)) = *(const short8*)(src + e);
            }
        }
        __syncthreads();

        // ---- chunk weight segment ----
        const unsigned short* Wseg; int kbase, kst; bool first_h;
        if (layer == 0) {
            if (c == 0) { Wseg = W0i; kbase = 0;           kst = DIN; first_h = false; }
            else        { Wseg = W0h; kbase = (c-1) * 512; kst = HID; first_h = (c == 1); }
        } else {
            if (c < 2)  { Wseg = W1i; kbase = c * 512;     kst = HID; first_h = false; }
            else        { Wseg = W1h; kbase = (c-2) * 512; kst = HID; first_h = (c == 2); }
        }
        if (first_h) { acc_nx = acc_n; acc_n = (f32x4){0,0,0,0}; }  // split n-gate: x-side vs h-side

        const int jrow = j0 + (l & 15);
        const int ksub = (l >> 4) << 3;                     // 8-elem K-subgroup per lane
        const unsigned short* wr = Wseg + (long)jrow            * kst + kbase + ksub;
        const unsigned short* wz = Wseg + (long)(HID   + jrow)  * kst + kbase + ksub;
        const unsigned short* wn = Wseg + (long)(2*HID + jrow)  * kst + kbase + ksub;
        const int arow = (w << 4) + (l & 15);

#pragma unroll
        for (int kk = 0; kk < 16; ++kk) {
            short8 a  = *(const short8*)(ldsA + SWZ(arow, (kk << 6) + (ksub << 1)));
            short8 br = *(const short8*)(wr + (kk << 5));
            short8 bz = *(const short8*)(wz + (kk << 5));
            short8 bn = *(const short8*)(wn + (kk << 5));
            acc_r = __builtin_amdgcn_mfma_f32_16x16x32_bf16(a, br, acc_r, 0, 0, 0);
            acc_z = __builtin_amdgcn_mfma_f32_16x16x32_bf16(a, bz, acc_z, 0, 0, 0);
            acc_n = __builtin_amdgcn_mfma_f32_16x16x32_bf16(a, bn, acc_n, 0, 0, 0);
        }
    }

    // ---- pointwise GRU update (thread-local: r/z/n accs share (row,col) map) ----
    const int j = j0 + (l & 15);
    const float* bi = layer ? bi1 : bi0;
    const float* bh = layer ? bh1 : bh0;
    const float bir = bi[j], biz = bi[HID + j], bin = bi[2*HID + j];
    const float bhr = bh[j], bhz = bh[HID + j], bhn = bh[2*HID + j];
    const long poff = (long)(layer*2 + rp) * NB * HID;
    const long noff = (long)(layer*2 + wp) * NB * HID;
#pragma unroll
    for (int v = 0; v < 4; ++v) {
        const int b = (w << 4) + ((l >> 4) << 2) + v;   // C/D: row=(lane>>4)*4+v, col=lane&15
        const float r = sigm_(acc_r[v] + bir + bhr);
        const float z = sigm_(acc_z[v] + biz + bhz);
        const float n = tanh_((acc_nx[v] + bin) + r * (acc_n[v] + bhn));
        const float hp = hf[poff + (long)b*HID + j];
        const float hnew = (1.0f - z) * hp + z * n;
        hf[noff + (long)b*HID + j] = hnew;
        hb[noff + (long)b*HID + j] = f2bf(hnew);
        if (layer) out[((long)b*SEQ + s)*HID + j] = hnew;
    }
}

__global__ __launch_bounds__(256) void cvt_bf16(const float* __restrict__ src,
                                                unsigned short* __restrict__ dst, int n4) {
    int i = blockIdx.x * 256 + threadIdx.x;
    if (i >= n4) return;
    float4 f = *(const float4*)(src + 4L*i);
    unsigned long long u =  (unsigned long long)f2bf(f.x)
                         | ((unsigned long long)f2bf(f.y) << 16)
                         | ((unsigned long long)f2bf(f.z) << 32)
                         | ((unsigned long long)f2bf(f.w) << 48);
    *(unsigned long long*)(dst + 4L*i) = u;
}

__global__ __launch_bounds__(256) void init_h(const float* __restrict__ h0,
                                              float* __restrict__ hf,
                                              unsigned short* __restrict__ hb) {
    int i = blockIdx.x * 256 + threadIdx.x;          // 2*64*1024 = 131072 threads
    int layer = i >> 16, idx = i & 65535;
    float v = h0[i];
    hf[(long)(layer*2 + 0)*65536 + idx] = v;          // parity 0
    hb[(long)(layer*2 + 0)*65536 + idx] = f2bf(v);
}

extern "C" void kernel_launch(void* const* d_in, const int* in_sizes, int n_in,
                              void* d_out, int out_size, void* d_ws, size_t ws_size,
                              hipStream_t stream) {
    const float* x    = (const float*)d_in[0];
    const float* h0   = (const float*)d_in[1];
    const float* Wih0 = (const float*)d_in[2];
    const float* Whh0 = (const float*)d_in[3];
    const float* bih0 = (const float*)d_in[4];
    const float* bhh0 = (const float*)d_in[5];
    const float* Wih1 = (const float*)d_in[6];
    const float* Whh1 = (const float*)d_in[7];
    const float* bih1 = (const float*)d_in[8];
    const float* bhh1 = (const float*)d_in[9];

    float* out   = (float*)d_out;                     // [64][512][1024]
    float* hnout = out + (long)NB * SEQ * HID;        // [2][64][1024]

    // ws layout (24 MiB total):
    unsigned short* W0i = (unsigned short*)d_ws;          // [3072][512]
    unsigned short* W0h = W0i + 3072L * 512;              // [3072][1024]
    unsigned short* W1i = W0h + 3072L * 1024;             // [3072][1024]
    unsigned short* W1h = W1i + 3072L * 1024;             // [3072][1024]
    float*          hf  = (float*)(W1h + 3072L * 1024);   // [2][2][64][1024] f32
    unsigned short* hb  = (unsigned short*)(hf + 4L * 65536); // same, bf16

    cvt_bf16<<<(3072*512/4  + 255)/256, 256, 0, stream>>>(Wih0, W0i, 3072*512/4);
    cvt_bf16<<<(3072*1024/4 + 255)/256, 256, 0, stream>>>(Whh0, W0h, 3072*1024/4);
    cvt_bf16<<<(3072*1024/4 + 255)/256, 256, 0, stream>>>(Wih1, W1i, 3072*1024/4);
    cvt_bf16<<<(3072*1024/4 + 255)/256, 256, 0, stream>>>(Whh1, W1h, 3072*1024/4);
    init_h<<<512, 256, 0, stream>>>(h0, hf, hb);

    for (int t = 0; t <= SEQ; ++t) {
        gru_step<<<128, 256, 0, stream>>>(t, x, W0i, W0h, W1i, W1h,
                                          bih0, bhh0, bih1, bhh1, hf, hb, out);
    }

    // final h: both layers' step 511 wrote parity 0
    hipMemcpyAsync(hnout,              hf,               65536*sizeof(float),
                   hipMemcpyDeviceToDevice, stream);
    hipMemcpyAsync(hnout + 65536,      hf + 2L*65536,    65536*sizeof(float),
                   hipMemcpyDeviceToDevice, stream);
}